// Round 12
// baseline (2043.910 us; speedup 1.0000x reference)
//
#include <hip/hip_runtime.h>
#include <hip/hip_bf16.h>

// R-GCN (2-layer) + mean-pool + linear + softmax, MI355X.
// v5: sum-then-transform. out[n] = sum_r (sum_{edges r->n} h[src]) @ W[r]
// (linearity => exact). Per 64-node tile: Phase A accumulates S[64][512]
// (per-(node,rel) feature sums) in 128KB LDS via 1 coalesced h-load + 1 LDS
// b32 RMW per edge; Phase B = dense S @ Wstack GEMM with lane=node, S rows
// per-lane (quad-rotated, bank-spread b128), W uniform-broadcast in
// double-buffered VGPRs. Kills v4's fundamental floor (E x K*64 W-reads from
// LDS = 750us): W now flows once per node-tile. Edges sorted by (dst,relhalf)
// so layer-2 passes touch only their own edges. No atomics anywhere hot.

#define IN_DIM 32
#define HID 64
#define NREL 16
#define NCLS 8
#define CHUNK 2048

__device__ __forceinline__ int rfl(int v) { return __builtin_amdgcn_readfirstlane(v); }
__device__ __forceinline__ int rl(int v, int l) { return __builtin_amdgcn_readlane(v, l); }

// ---------------- (dst, relhalf) histogram + scan -> rowptr2 ----------------

__global__ void hist_dst2_k(const int* __restrict__ dst, const int* __restrict__ rel,
                            int* __restrict__ histd2, int E) {
  for (int e = blockIdx.x * blockDim.x + threadIdx.x; e < E; e += gridDim.x * blockDim.x)
    atomicAdd(&histd2[dst[e] * 2 + (rel[e] >> 3)], 1);
}

__global__ void scan1_k(const int* __restrict__ histd, int* __restrict__ csum, int N) {
  __shared__ int red[256];
  int t = threadIdx.x;
  int base = blockIdx.x * CHUNK + t * 8;
  int s = 0;
#pragma unroll
  for (int i = 0; i < 8; ++i) { int idx = base + i; s += (idx < N) ? histd[idx] : 0; }
  red[t] = s; __syncthreads();
  for (int off = 128; off > 0; off >>= 1) {
    if (t < off) red[t] += red[t + off];
    __syncthreads();
  }
  if (t == 0) csum[blockIdx.x] = red[0];
}

__global__ void scan2_k(const int* __restrict__ csum, int* __restrict__ cbase,
                        int* __restrict__ rowptr, int nchunks, int N) {
  if (threadIdx.x == 0) {
    int run = 0;
    for (int c = 0; c < nchunks; ++c) { cbase[c] = run; run += csum[c]; }
    rowptr[N] = run;
  }
}

__global__ void scan3_k(const int* __restrict__ histd, const int* __restrict__ cbase,
                        int* __restrict__ rowptr, int* __restrict__ filldst, int N) {
  __shared__ int ts[256];
  int t = threadIdx.x;
  int base = blockIdx.x * CHUNK + t * 8;
  int v[8]; int s = 0;
#pragma unroll
  for (int i = 0; i < 8; ++i) { int idx = base + i; int x = (idx < N) ? histd[idx] : 0; v[i] = x; s += x; }
  ts[t] = s; __syncthreads();
  int x = s;
  for (int off = 1; off < 256; off <<= 1) {
    int y = (t >= off) ? ts[t - off] : 0;
    __syncthreads();
    x += y; ts[t] = x;
    __syncthreads();
  }
  int run = cbase[blockIdx.x] + x - s;
#pragma unroll
  for (int i = 0; i < 8; ++i) {
    int idx = base + i;
    if (idx < N) { rowptr[idx] = run; filldst[idx] = run; run += v[i]; }
  }
}

__global__ void scatter_pack2(const int* __restrict__ src, const int* __restrict__ dst,
                              const int* __restrict__ rel, int* __restrict__ filldst2,
                              int* __restrict__ epack, int E) {
  int e = blockIdx.x * blockDim.x + threadIdx.x;
  if (e < E) {
    int q = atomicAdd(&filldst2[dst[e] * 2 + (rel[e] >> 3)], 1);
    epack[q] = (src[e] << 4) | rel[e];
  }
}

// ---------------- v5 fused tile kernel ----------------
// Tile = 64 nodes. LDS S[64][512]: node row rotated by quad:
//   float (nl, d) -> lw[nl*512 + 4*(((d>>2) + nl) & 127) + (d&3)]
// Phase A: per edge, lanes=feature i: S[nl][rloc*K + i] += h[src][i].
// Phase B: lane=node; acc[8 outputs]; W chunk (8d x 8o) uniform-broadcast in
// VGPR float4s, double-buffered; S read as rotated b128 quads.

__device__ __forceinline__ void loadw16(float4* buf, const float* __restrict__ Wb,
                                        int dgw, int o0) {
#pragma unroll
  for (int dd = 0; dd < 8; ++dd) {
    const float* p = Wb + (dgw * 8 + dd) * 64 + o0;
    buf[2 * dd]     = *(const float4*)(p);
    buf[2 * dd + 1] = *(const float4*)(p + 4);
  }
}

__device__ __forceinline__ void fma8(float* acc, const float4 s0, const float4 s1,
                                     const float4* w) {
#pragma unroll
  for (int dd = 0; dd < 8; ++dd) {
    const float sv = (dd == 0) ? s0.x : (dd == 1) ? s0.y : (dd == 2) ? s0.z :
                     (dd == 3) ? s0.w : (dd == 4) ? s1.x : (dd == 5) ? s1.y :
                     (dd == 6) ? s1.z : s1.w;
    const float4 wa = w[2 * dd], wb = w[2 * dd + 1];
    acc[0] = fmaf(sv, wa.x, acc[0]); acc[1] = fmaf(sv, wa.y, acc[1]);
    acc[2] = fmaf(sv, wa.z, acc[2]); acc[3] = fmaf(sv, wa.w, acc[3]);
    acc[4] = fmaf(sv, wb.x, acc[4]); acc[5] = fmaf(sv, wb.y, acc[5]);
    acc[6] = fmaf(sv, wb.z, acc[6]); acc[7] = fmaf(sv, wb.w, acc[7]);
  }
}

template <int K, bool ACC, bool BOTH>
__global__ __launch_bounds__(512, 2)
void edge_tile(const float* __restrict__ hin, const int* __restrict__ epack,
               const int* __restrict__ rowptr2, const float* __restrict__ W,
               float* __restrict__ out, int N, int g) {
  constexpr int GSZ = 512 / K;
  __shared__ float lw[64 * 512];          // 128 KB
  const int tid = threadIdx.x;
  const int lane = tid & 63;
  const int wv = tid >> 6;                // wave 0..7
  const int n0 = blockIdx.x * 64;

  // zero S
  for (int i = tid * 4; i < 64 * 512; i += 512 * 4)
    *(float4*)(lw + i) = make_float4(0.f, 0.f, 0.f, 0.f);
  __syncthreads();

  // ---- phase A: per-(node,rel) sums ----
  for (int s = 0; s < 8; ++s) {
    const int nl = wv * 8 + s;
    const int n = n0 + nl;
    if (n < N) {
      int j0, j1;
      if (BOTH) { j0 = rowptr2[2 * n];     j1 = rowptr2[2 * n + 2]; }
      else      { j0 = rowptr2[2 * n + g]; j1 = rowptr2[2 * n + g + 1]; }
#pragma unroll 4
      for (int j = j0; j < j1; ++j) {
        const int ep = epack[j];
        const int rloc = ep & (GSZ - 1);
        const int src = ep >> 4;
        if (K == 64) {
          const float hv = hin[(size_t)src * 64 + lane];
          const int d = rloc * 64 + lane;
          const int fi = nl * 512 + 4 * (((d >> 2) + nl) & 127) + (d & 3);
          lw[fi] += hv;
        } else {
          if (lane < 32) {
            const float hv = hin[(size_t)src * 32 + lane];
            const int d = rloc * 32 + lane;
            const int fi = nl * 512 + 4 * (((d >> 2) + nl) & 127) + (d & 3);
            lw[fi] += hv;
          }
        }
      }
    }
  }
  __syncthreads();

  // ---- phase B: OUT[64][64] = S[64][512] @ Wstack[512][64] ----
  const int o0 = wv * 8;
  const float* __restrict__ Wb = W + (size_t)g * (GSZ * K * 64);
  float4 wc[16], wn[16];
  float acc[8];
#pragma unroll
  for (int oo = 0; oo < 8; ++oo) acc[oo] = 0.f;
  const int myrow = lane * 512;

  loadw16(wc, Wb, 0, o0);
  for (int dg = 0; dg < 64; dg += 2) {
    loadw16(wn, Wb, (dg + 1) & 63, o0);
    {
      const float4 s0 = *(const float4*)(lw + myrow + 4 * ((2 * dg + lane) & 127));
      const float4 s1 = *(const float4*)(lw + myrow + 4 * ((2 * dg + 1 + lane) & 127));
      fma8(acc, s0, s1, wc);
    }
    loadw16(wc, Wb, (dg + 2) & 63, o0);
    {
      const float4 s0 = *(const float4*)(lw + myrow + 4 * ((2 * dg + 2 + lane) & 127));
      const float4 s1 = *(const float4*)(lw + myrow + 4 * ((2 * dg + 3 + lane) & 127));
      fma8(acc, s0, s1, wn);
    }
  }

  const int n = n0 + lane;                // lane = node
  if (n < N) {
    float* dp = out + (size_t)n * 64 + o0;
    if (ACC) {
      float4 a = *(float4*)(dp), b = *(float4*)(dp + 4);
      a.x += acc[0]; a.y += acc[1]; a.z += acc[2]; a.w += acc[3];
      b.x += acc[4]; b.y += acc[5]; b.z += acc[6]; b.w += acc[7];
      *(float4*)(dp) = a; *(float4*)(dp + 4) = b;
    } else {
      *(float4*)(dp)     = make_float4(acc[0], acc[1], acc[2], acc[3]);
      *(float4*)(dp + 4) = make_float4(acc[4], acc[5], acc[6], acc[7]);
    }
  }
}

// ---------------- finalize: self-loop + bias + relu (measured-correct) ----------------

__global__ void finalize1(const float* __restrict__ agg, const float* __restrict__ h,
                          const float* __restrict__ Wl, const float* __restrict__ b,
                          float* __restrict__ h1, int N) {
  const int lane = threadIdx.x & 63;
  int wid = rfl((int)(blockIdx.x * (blockDim.x >> 6) + (threadIdx.x >> 6)));
  int nw = gridDim.x * (blockDim.x >> 6);
  float wl[IN_DIM];
#pragma unroll
  for (int i = 0; i < IN_DIM; ++i) wl[i] = Wl[i * HID + lane];
  float bv = b[lane];
  for (int n = wid; n < N; n += nw) {
    const float4* __restrict__ row = (const float4*)(h + (size_t)n * IN_DIM);
    float a0 = 0.f, a1 = 0.f, a2 = 0.f, a3 = 0.f;
#pragma unroll
    for (int i = 0; i < IN_DIM / 4; ++i) {
      float4 hv = row[i];
      a0 = fmaf(hv.x, wl[4 * i + 0], a0);
      a1 = fmaf(hv.y, wl[4 * i + 1], a1);
      a2 = fmaf(hv.z, wl[4 * i + 2], a2);
      a3 = fmaf(hv.w, wl[4 * i + 3], a3);
    }
    float v = agg[(size_t)n * HID + lane] + (a0 + a1) + (a2 + a3) + bv;
    h1[(size_t)n * HID + lane] = fmaxf(v, 0.f);
  }
}

__global__ void finalize2_pool(const float* __restrict__ agg, const float* __restrict__ h1,
                               const float* __restrict__ Wl, const float* __restrict__ b,
                               const int* __restrict__ n2g,
                               float* __restrict__ pooled, float* __restrict__ cnt, int N) {
  const int lane = threadIdx.x & 63;
  int wid = rfl((int)(blockIdx.x * (blockDim.x >> 6) + (threadIdx.x >> 6)));
  int nw = gridDim.x * (blockDim.x >> 6);
  int per = (N + nw - 1) / nw;
  int n0 = wid * per, n1 = min(N, n0 + per);
  if (n0 >= n1) return;
  float wl[HID];
#pragma unroll
  for (int i = 0; i < HID; ++i) wl[i] = Wl[i * HID + lane];
  float bv = b[lane];
  float psum = 0.f, pcnt = 0.f;
  int pg = -1;
  for (int n = n0; n < n1; ++n) {
    const float4* __restrict__ row = (const float4*)(h1 + (size_t)n * HID);
    float a0 = 0.f, a1 = 0.f, a2 = 0.f, a3 = 0.f;
#pragma unroll
    for (int i = 0; i < HID / 4; ++i) {
      float4 hv = row[i];
      a0 = fmaf(hv.x, wl[4 * i + 0], a0);
      a1 = fmaf(hv.y, wl[4 * i + 1], a1);
      a2 = fmaf(hv.z, wl[4 * i + 2], a2);
      a3 = fmaf(hv.w, wl[4 * i + 3], a3);
    }
    float v = agg[(size_t)n * HID + lane] + (a0 + a1) + (a2 + a3) + bv;
    v = fmaxf(v, 0.f);
    int g = rfl(n2g[n]);
    if (g != pg) {
      if (pg >= 0) {
        atomicAdd(&pooled[(size_t)pg * HID + lane], psum);
        if (lane == 0) atomicAdd(&cnt[pg], pcnt);
      }
      pg = g; psum = 0.f; pcnt = 0.f;
    }
    psum += v; pcnt += 1.f;
  }
  if (pg >= 0) {
    atomicAdd(&pooled[(size_t)pg * HID + lane], psum);
    if (lane == 0) atomicAdd(&cnt[pg], pcnt);
  }
}

// ---------------- classifier + softmax ----------------

__global__ void classifier(const float* __restrict__ pooled, const float* __restrict__ cnt,
                           const float* __restrict__ Wc, const float* __restrict__ bc,
                           float* __restrict__ out, int B) {
  int g = blockIdx.x * blockDim.x + threadIdx.x;
  if (g >= B) return;
  float c = fmaxf(cnt[g], 1.f);
  float lg[NCLS];
#pragma unroll
  for (int cc = 0; cc < NCLS; ++cc) lg[cc] = bc[cc];
  for (int k = 0; k < HID; ++k) {
    float hg = pooled[(size_t)g * HID + k] / c;
#pragma unroll
    for (int cc = 0; cc < NCLS; ++cc) lg[cc] = fmaf(hg, Wc[k * NCLS + cc], lg[cc]);
  }
  float m = lg[0];
#pragma unroll
  for (int cc = 1; cc < NCLS; ++cc) m = fmaxf(m, lg[cc]);
  float s = 0.f;
#pragma unroll
  for (int cc = 0; cc < NCLS; ++cc) { lg[cc] = __expf(lg[cc] - m); s += lg[cc]; }
  float inv = 1.f / s;
#pragma unroll
  for (int cc = 0; cc < NCLS; ++cc) out[(size_t)g * NCLS + cc] = lg[cc] * inv;
}

// ---------------- fallback (round-5 measured-correct atomic path) ----------------

__global__ void hist_rel(const int* __restrict__ rel, int* __restrict__ hist, int E) {
  __shared__ int lh[NREL];
  int tid = threadIdx.x;
  if (tid < NREL) lh[tid] = 0;
  __syncthreads();
  for (int e = blockIdx.x * blockDim.x + tid; e < E; e += gridDim.x * blockDim.x)
    atomicAdd(&lh[rel[e]], 1);
  __syncthreads();
  if (tid < NREL && lh[tid] > 0) atomicAdd(&hist[tid], lh[tid]);
}

__global__ void scan16(const int* __restrict__ hist, int* __restrict__ offs,
                       int* __restrict__ fill) {
  if (threadIdx.x == 0) {
    int o = 0;
    for (int r = 0; r < NREL; ++r) {
      offs[r] = o; fill[r] = o;
      o += (hist[r] + 63) & ~63;
    }
    offs[NREL] = o;
  }
}

__global__ void fill_pad(int* __restrict__ ssrc, int* __restrict__ sdst, int Epad, int N) {
  int i = blockIdx.x * blockDim.x + threadIdx.x;
  if (i < Epad) { ssrc[i] = 0; sdst[i] = N; }
}

__global__ void scatter_rel(const int* __restrict__ rel, const int* __restrict__ src,
                            const int* __restrict__ dst, int* __restrict__ fill,
                            int* __restrict__ ssrc, int* __restrict__ sdst, int E) {
  __shared__ int lc[NREL];
  __shared__ int lbase[NREL];
  int tid = threadIdx.x;
  if (tid < NREL) lc[tid] = 0;
  __syncthreads();
  int e = blockIdx.x * blockDim.x + tid;
  int r = 0, lo = 0;
  bool valid = (e < E);
  if (valid) { r = rel[e]; lo = atomicAdd(&lc[r], 1); }
  __syncthreads();
  if (tid < NREL && lc[tid] > 0) lbase[tid] = atomicAdd(&fill[tid], lc[tid]);
  __syncthreads();
  if (valid) { int p = lbase[r] + lo; ssrc[p] = src[e]; sdst[p] = dst[e]; }
}

template <int IN>
__global__ void edge_layer(const float* __restrict__ hin, const int* __restrict__ ssrc,
                           const int* __restrict__ sdst, const float* __restrict__ W,
                           const int* __restrict__ offs, float* __restrict__ agg,
                           int maxchunks) {
  const int lane = threadIdx.x & 63;
  int wid = rfl((int)(blockIdx.x * (blockDim.x >> 6) + (threadIdx.x >> 6)));
  if (wid >= maxchunks) return;
  const int base = wid * 64;
  int r = 0;
#pragma unroll
  for (int k = 1; k < NREL; ++k) r += (base >= offs[k]) ? 1 : 0;
  const float* Wr = W + (size_t)r * (IN * HID);
  float w[IN];
#pragma unroll
  for (int i = 0; i < IN; ++i) w[i] = Wr[i * HID + lane];
  const int myd = sdst[base + lane];
  const int mys = ssrc[base + lane];
#pragma unroll 4
  for (int k = 0; k < 64; ++k) {
    const int d = rl(myd, k);
    const int s = rl(mys, k);
    const float4* __restrict__ row = (const float4*)(hin + (size_t)s * IN);
    float a0 = 0.f, a1 = 0.f, a2 = 0.f, a3 = 0.f;
#pragma unroll
    for (int i = 0; i < IN / 4; ++i) {
      float4 hv = row[i];
      a0 = fmaf(hv.x, w[4 * i + 0], a0);
      a1 = fmaf(hv.y, w[4 * i + 1], a1);
      a2 = fmaf(hv.z, w[4 * i + 2], a2);
      a3 = fmaf(hv.w, w[4 * i + 3], a3);
    }
    atomicAdd(&agg[(size_t)d * HID + lane], (a0 + a1) + (a2 + a3));
  }
}

// ---------------- launch ----------------

extern "C" void kernel_launch(void* const* d_in, const int* in_sizes, int n_in,
                              void* d_out, int out_size, void* d_ws, size_t ws_size,
                              hipStream_t stream) {
  const float* h   = (const float*)d_in[0];
  const int* src   = (const int*)d_in[1];
  const int* dst   = (const int*)d_in[2];
  const int* rel   = (const int*)d_in[3];
  const int* n2g   = (const int*)d_in[4];
  const float* W1  = (const float*)d_in[5];
  const float* Wl1 = (const float*)d_in[6];
  const float* b1  = (const float*)d_in[7];
  const float* W2  = (const float*)d_in[8];
  const float* Wl2 = (const float*)d_in[9];
  const float* b2  = (const float*)d_in[10];
  const float* Wc  = (const float*)d_in[11];
  const float* bc  = (const float*)d_in[12];

  const int N = in_sizes[0] / IN_DIM;
  const int E = in_sizes[1];
  const int B = out_size / NCLS;
  const int N2 = 2 * N;
  const int nch2 = (N2 + CHUNK - 1) / CHUNK;
  const int nt = (N + 63) / 64;

  // ---- v5 workspace (4B elems ~60MB): tmp | h1 | epack | rowptr2(2N+1) |
  //      filldst2(2N) | histd2(2N) | csum | cbase | pooled | cnt ----
  size_t need = (size_t)N * HID * 2 + (size_t)E + (size_t)(N2 + 1) + 2 * (size_t)N2 +
                2 * (size_t)nch2 + (size_t)B * HID + B + 64;
  if (ws_size >= need * 4) {
    float* tmp     = (float*)d_ws;
    float* h1      = tmp + (size_t)N * HID;
    int*   epack   = (int*)(h1 + (size_t)N * HID);
    int*   rowptr2 = epack + E;
    int*   filldst2= rowptr2 + (N2 + 1);
    int*   histd2  = filldst2 + N2;
    int*   csum    = histd2 + N2;
    int*   cbase   = csum + nch2;
    float* pooled  = (float*)(cbase + nch2);
    float* cnt     = pooled + (size_t)B * HID;

    hipMemsetAsync(histd2, 0, (size_t)N2 * sizeof(int), stream);
    hipMemsetAsync(pooled, 0, (size_t)(B * HID + B) * sizeof(float), stream);

    hist_dst2_k<<<1024, 256, 0, stream>>>(dst, rel, histd2, E);
    scan1_k<<<nch2, 256, 0, stream>>>(histd2, csum, N2);
    scan2_k<<<1, 64, 0, stream>>>(csum, cbase, rowptr2, nch2, N2);
    scan3_k<<<nch2, 256, 0, stream>>>(histd2, cbase, rowptr2, filldst2, N2);
    scatter_pack2<<<(E + 255) / 256, 256, 0, stream>>>(src, dst, rel, filldst2, epack, E);

    // layer 1: K=32, all 16 rels (D=512), single pass over both rel-halves
    edge_tile<32, false, true><<<nt, 512, 0, stream>>>(h, epack, rowptr2, W1, tmp, N, 0);
    finalize1<<<2048, 256, 0, stream>>>(tmp, h, Wl1, b1, h1, N);

    // layer 2: K=64, 8 rels per pass (D=512), 2 passes
    edge_tile<64, false, false><<<nt, 512, 0, stream>>>(h1, epack, rowptr2, W2, tmp, N, 0);
    edge_tile<64, true,  false><<<nt, 512, 0, stream>>>(h1, epack, rowptr2, W2, tmp, N, 1);
    finalize2_pool<<<2048, 256, 0, stream>>>(tmp, h1, Wl2, b2, n2g, pooled, cnt, N);

    classifier<<<(B + 127) / 128, 128, 0, stream>>>(pooled, cnt, Wc, bc, (float*)d_out, B);
    return;
  }

  // ---- fallback: round-5 measured-correct atomic path ----
  const int maxchunks = (E + 63) / 64 + NREL;
  const int Epad = maxchunks * 64;
  const int eblocks = (maxchunks + 3) / 4;
  float* agg    = (float*)d_ws;
  float* h1     = agg + (size_t)(N + 1) * HID;
  int*   ssrc   = (int*)(h1 + (size_t)N * HID);
  int*   sdst   = ssrc + Epad;
  int*   hist   = sdst + Epad;
  int*   offs   = hist + NREL;
  int*   fill   = offs + NREL + 1;
  float* pooled = (float*)(fill + NREL);
  float* cnt    = pooled + (size_t)B * HID;

  hipMemsetAsync(hist, 0, NREL * sizeof(int), stream);
  hipMemsetAsync(pooled, 0, (size_t)(B * HID + B) * sizeof(float), stream);
  fill_pad<<<(Epad + 255) / 256, 256, 0, stream>>>(ssrc, sdst, Epad, N);
  hist_rel<<<1024, 256, 0, stream>>>(rel, hist, E);
  scan16<<<1, 64, 0, stream>>>(hist, offs, fill);
  scatter_rel<<<(E + 255) / 256, 256, 0, stream>>>(rel, src, dst, fill, ssrc, sdst, E);
  hipMemsetAsync(agg, 0, (size_t)(N + 1) * HID * sizeof(float), stream);
  edge_layer<IN_DIM><<<eblocks, 256, 0, stream>>>(h, ssrc, sdst, W1, offs, agg, maxchunks);
  finalize1<<<2048, 256, 0, stream>>>(agg, h, Wl1, b1, h1, N);
  hipMemsetAsync(agg, 0, (size_t)(N + 1) * HID * sizeof(float), stream);
  edge_layer<HID><<<eblocks, 256, 0, stream>>>(h1, ssrc, sdst, W2, offs, agg, maxchunks);
  finalize2_pool<<<2048, 256, 0, stream>>>(agg, h1, Wl2, b2, n2g, pooled, cnt, N);
  classifier<<<(B + 127) / 128, 128, 0, stream>>>(pooled, cnt, Wc, bc, (float*)d_out, B);
}